// Round 7
// baseline (50913.181 us; speedup 1.0000x reference)
//
#include <hip/hip_runtime.h>
#include <stdint.h>

#define T_STEPS 8192
#define HID     1024
#define IN_F    2048
#define N3H     3072   // 3*HID
#define NREP    8      // exchange-buffer replicas (spread coherence-point lines)

// ---------------------------------------------------------------------------
// Exchange format: one u32 per h element; low 2 mantissa bits = step tag
// (step & 3). Double-buffered (buffer s&1 holds h of step s); stale content
// is from step s-2 (tag differs mod 4). Full-vector detection bounds skew
// below 2 steps (now per-WAVE: a wave passes head k only after observing all
// 1024 words of h^k), so neither past (s-4) nor future (s+4) mod-4 aliases
// can be observed: monotone coherence-point reads exclude older, and no
// producer writes h^{k+2} into buffer k&1 until every wave stored h^{k+1},
// i.e. passed head k. Producers store to every replica; wave owning j polls
// replica j&(NREP-1) only. h_0 = 0.0f with tag 0 == 0x0 -> zero-init.
//
// r7 STRUCTURE: 1024 independent waves, one per output j. No LDS, no
// barriers in the scan loop. Weights live in registers (12 float4/lane).
// The whole h vector is probed in ONE fused asm: 4 concurrent
// global_load_dwordx4 + a single s_waitcnt vmcnt(0); outputs are complete
// at the asm boundary (r6 safety discipline: no split issue/wait, no
// in-flight load with compiler-dead destination). "=&v" early-clobber keeps
// outputs disjoint from the 4 address-pair inputs. Poll exit is wave-uniform
// (__all) so every probe executes full-exec and fully redefines its
// destinations; re-reading already-good words is monotone-safe.
// ---------------------------------------------------------------------------
__global__ void init_pairs(unsigned int* pairs) {
    int i = blockIdx.x * blockDim.x + threadIdx.x;
    if (i < 2 * NREP * HID) pairs[i] = 0u;
}

// fused scoped 4x16B probe: bypass L1/L2 (sc0 sc1) so cross-XCD stores are
// visible; per-32-bit-word atomicity from natural alignment (tearing across
// words fine -- each word carries its own tag). All 4 loads in flight
// concurrently -> ONE round trip for 64B/lane; vmcnt(0) INSIDE the asm.
__device__ __forceinline__ void probe4(uint4& r0, uint4& r1, uint4& r2, uint4& r3,
                                       const unsigned int* p0, const unsigned int* p1,
                                       const unsigned int* p2, const unsigned int* p3) {
    asm volatile(
        "global_load_dwordx4 %0, %4, off sc0 sc1\n\t"
        "global_load_dwordx4 %1, %5, off sc0 sc1\n\t"
        "global_load_dwordx4 %2, %6, off sc0 sc1\n\t"
        "global_load_dwordx4 %3, %7, off sc0 sc1\n\t"
        "s_waitcnt vmcnt(0)"
        : "=&v"(r0), "=&v"(r1), "=&v"(r2), "=&v"(r3)
        : "v"(p0), "v"(p1), "v"(p2), "v"(p3)
        : "memory");
}
__device__ __forceinline__ void store_scoped(unsigned int* p, unsigned int v) {
    asm volatile("global_store_dword %0, %1, off sc0 sc1"
                 :: "v"(p), "v"(v) : "memory");
}
// low-2-bit tag match across all 16 words: OR of (word^want) has clear low bits
__device__ __forceinline__ int tag16_ok(const uint4& a, const uint4& b,
                                        const uint4& c, const uint4& d,
                                        unsigned int w) {
    unsigned int x = (a.x ^ w) | (a.y ^ w) | (a.z ^ w) | (a.w ^ w)
                   | (b.x ^ w) | (b.y ^ w) | (b.z ^ w) | (b.w ^ w)
                   | (c.x ^ w) | (c.y ^ w) | (c.z ^ w) | (c.w ^ w)
                   | (d.x ^ w) | (d.y ^ w) | (d.z ^ w) | (d.w ^ w);
    return (x & 3u) == 0u;
}
__device__ __forceinline__ float dot4(const float4& a, const float4& b) {
    return a.x * b.x + a.y * b.y + a.z * b.z + a.w * b.w;
}
__device__ __forceinline__ float4 u4_as_f4(const uint4& u) {
    float4 f;
    f.x = __uint_as_float(u.x); f.y = __uint_as_float(u.y);
    f.z = __uint_as_float(u.z); f.w = __uint_as_float(u.w);
    return f;
}

// ---------------------------------------------------------------------------
// Phase 1: gi[t, j'] = x[t] . w_ih[j'] + b_ih[j']  (unchanged, ~1.4 ms)
// ---------------------------------------------------------------------------
#define GBM 64
#define GBN 64
#define GBK 32

__global__ __launch_bounds__(256) void gi_gemm(
    const float* __restrict__ feat,   // [8192][2048]
    const float* __restrict__ rew,    // [8192]
    const float* __restrict__ w_ih,   // [3072][2049]
    const float* __restrict__ b_ih,   // [3072]
    float* __restrict__ gi)           // [8192][3072]
{
    __shared__ float As[GBK][GBM + 4];
    __shared__ float Bs[GBK][GBN + 4];

    const int tid = threadIdx.x;
    const int n0 = blockIdx.x * GBN;
    const int t0 = blockIdx.y * GBM;
    const int tx = tid & 15, ty = tid >> 4;
    const int lr = tid >> 3;
    const int lc = (tid & 7) * 4;

    float acc[4][4] = {{0.f}};

    for (int k0 = 0; k0 < IN_F; k0 += GBK) {
#pragma unroll
        for (int hh = 0; hh < 2; hh++) {
            const int r = lr + 32 * hh;
            const float4 a = *(const float4*)(feat + (size_t)(t0 + r) * IN_F + k0 + lc);
            As[lc + 0][r] = a.x; As[lc + 1][r] = a.y;
            As[lc + 2][r] = a.z; As[lc + 3][r] = a.w;
            const float* brow = w_ih + (size_t)(n0 + r) * (IN_F + 1) + k0 + lc;
            Bs[lc + 0][r] = brow[0]; Bs[lc + 1][r] = brow[1];
            Bs[lc + 2][r] = brow[2]; Bs[lc + 3][r] = brow[3];
        }
        __syncthreads();
#pragma unroll
        for (int kk = 0; kk < GBK; kk++) {
            const float4 a = *(const float4*)&As[kk][ty * 4];
            const float4 b = *(const float4*)&Bs[kk][tx * 4];
            acc[0][0] += a.x * b.x; acc[0][1] += a.x * b.y; acc[0][2] += a.x * b.z; acc[0][3] += a.x * b.w;
            acc[1][0] += a.y * b.x; acc[1][1] += a.y * b.y; acc[1][2] += a.y * b.z; acc[1][3] += a.y * b.w;
            acc[2][0] += a.z * b.x; acc[2][1] += a.z * b.y; acc[2][2] += a.z * b.z; acc[2][3] += a.z * b.w;
            acc[3][0] += a.w * b.x; acc[3][1] += a.w * b.y; acc[3][2] += a.w * b.z; acc[3][3] += a.w * b.w;
        }
        __syncthreads();
    }

    const int m = t0 + ty * 4;
    const int n = n0 + tx * 4;
    float wlast[4], bi[4];
#pragma unroll
    for (int c = 0; c < 4; c++) {
        wlast[c] = w_ih[(size_t)(n + c) * (IN_F + 1) + IN_F];
        bi[c]    = b_ih[n + c];
    }
#pragma unroll
    for (int r = 0; r < 4; r++) {
        const float rwv = rew[m + r];
        float4 v;
        v.x = acc[r][0] + rwv * wlast[0] + bi[0];
        v.y = acc[r][1] + rwv * wlast[1] + bi[1];
        v.z = acc[r][2] + rwv * wlast[2] + bi[2];
        v.w = acc[r][3] + rwv * wlast[3] + bi[3];
        *(float4*)(gi + (size_t)(m + r) * N3H + n) = v;
    }
}

// ---------------------------------------------------------------------------
// Phase 2: persistent GRU scan. 256 wgs x 256 threads = 1024 INDEPENDENT
// waves; wave w of wg g owns output j = 4g+w. No LDS, no barriers in the
// loop. Weights in registers: lane l holds w_hh[gate*HID+j][c*256+4l .. +3]
// for gate=0..2, c=0..3 (12 float4 = 48 VGPR). Per step: one fused 4-load
// probe pulls all of h (64B/lane) in ONE RTT; FMA against weight regs;
// shfl_xor butterfly gives the 3 sums to ALL lanes; all lanes compute the
// gates redundantly (SIMD-free); lanes 0..7 store the 8 replicas in one
// predicated store issue. Own h[j] carried in a register (exact, untagged).
// ---------------------------------------------------------------------------
__global__ __launch_bounds__(256, 1) void gru_scan(
    const float* __restrict__ gi,     // [8192][3072]
    const float* __restrict__ w_hh,   // [3072][1024]
    const float* __restrict__ b_hh,   // [3072]
    unsigned int* pairs,              // [2][NREP][1024] tagged fp32
    float* __restrict__ out)          // [1024]
{
    const int tid  = threadIdx.x;
    const int g    = blockIdx.x;      // 0..255
    const int wave = tid >> 6;
    const int lane = tid & 63;
    const int j    = g * 4 + wave;    // 0..1023, this wave's output
    const int rep  = j & (NREP - 1);

    // weights into registers (static indices only -- rule #20)
    float4 wreg[3][4];
#pragma unroll
    for (int gate = 0; gate < 3; ++gate)
#pragma unroll
        for (int c = 0; c < 4; ++c)
            wreg[gate][c] = *(const float4*)(
                w_hh + (size_t)(gate * HID + j) * HID + c * 256 + 4 * lane);

    // biases: uniform-address loads, all lanes (broadcast fetch)
    const float b_r = b_hh[j];
    const float b_z = b_hh[HID + j];
    const float b_n = b_hh[2 * HID + j];

    float hj = 0.f;   // own h[j], exact

    for (int i = 0; i < T_STEPS; ++i) {
        const int t = T_STEPS - 1 - i;
        const unsigned int want = (unsigned int)(i & 3);
        const unsigned int* rbuf =
            pairs + ((size_t)(i & 1) * NREP + rep) * HID;
        const unsigned int* p0 = rbuf +   0 + 4 * lane;
        const unsigned int* p1 = rbuf + 256 + 4 * lane;
        const unsigned int* p2 = rbuf + 512 + 4 * lane;
        const unsigned int* p3 = rbuf + 768 + 4 * lane;

        // gi for this step: uniform-address loads (1 fetch, broadcast);
        // issued before the probe, drained by the probe's vmcnt(0).
        const float* girow = gi + (size_t)t * N3H + j;
        const float gi_r = girow[0];
        const float gi_z = girow[HID];
        const float gi_n = girow[2 * HID];

        // poll: one-RTT full-vector probe, wave-uniform exit.
        uint4 r0, r1, r2, r3;
        for (;;) {
            probe4(r0, r1, r2, r3, p0, p1, p2, p3);
            if (__all(tag16_ok(r0, r1, r2, r3, want))) break;
        }

        // 3 dots, straight from probe regs x weight regs
        float ar, az, an;
        {
            const float4 h0 = u4_as_f4(r0);
            ar  = dot4(h0, wreg[0][0]); az  = dot4(h0, wreg[1][0]); an  = dot4(h0, wreg[2][0]);
            const float4 h1 = u4_as_f4(r1);
            ar += dot4(h1, wreg[0][1]); az += dot4(h1, wreg[1][1]); an += dot4(h1, wreg[2][1]);
            const float4 h2 = u4_as_f4(r2);
            ar += dot4(h2, wreg[0][2]); az += dot4(h2, wreg[1][2]); an += dot4(h2, wreg[2][2]);
            const float4 h3 = u4_as_f4(r3);
            ar += dot4(h3, wreg[0][3]); az += dot4(h3, wreg[1][3]); an += dot4(h3, wreg[2][3]);
        }
        // butterfly: full sums on ALL lanes
#pragma unroll
        for (int off = 32; off > 0; off >>= 1) {
            ar += __shfl_xor(ar, off);
            az += __shfl_xor(az, off);
            an += __shfl_xor(an, off);
        }

        // gates (redundant on all lanes -- SIMD-free)
        const float r = 1.f / (1.f + __expf(-(gi_r + ar + b_r)));
        const float z = 1.f / (1.f + __expf(-(gi_z + az + b_z)));
        const float n = tanhf(gi_n + r * (an + b_n));
        const float hnew = (1.f - z) * n + z * hj;
        hj = hnew;

        if (i == T_STEPS - 1) {
            if (lane == 0) out[j] = hnew;
        } else {
            const unsigned int pk =
                (__float_as_uint(hnew) & ~3u) | (unsigned int)((i + 1) & 3);
            unsigned int* sbase =
                pairs + (size_t)((i + 1) & 1) * NREP * HID + j;
            // one predicated issue covers all 8 replicas (lanes 0..7)
            if (lane < NREP) store_scoped(sbase + lane * HID, pk);
        }
    }
}

// ---------------------------------------------------------------------------
extern "C" void kernel_launch(void* const* d_in, const int* in_sizes, int n_in,
                              void* d_out, int out_size, void* d_ws, size_t ws_size,
                              hipStream_t stream) {
    const float* feat = (const float*)d_in[0];  // [8192,2048]
    const float* rew  = (const float*)d_in[1];  // [8192]
    const float* w_ih = (const float*)d_in[2];  // [3072,2049]
    const float* w_hh = (const float*)d_in[3];  // [3072,1024]
    const float* b_ih = (const float*)d_in[4];  // [3072]
    const float* b_hh = (const float*)d_in[5];  // [3072]
    float* out = (float*)d_out;                 // [1024]

    float* gi = (float*)d_ws;                                   // 96 MB
    unsigned int* pairs =
        (unsigned int*)((char*)d_ws + (size_t)T_STEPS * N3H * sizeof(float));  // 64 KB

    hipLaunchKernelGGL(init_pairs, dim3((2 * NREP * HID + 255) / 256), dim3(256), 0, stream, pairs);
    hipLaunchKernelGGL(gi_gemm, dim3(N3H / GBN, T_STEPS / GBM), dim3(256), 0, stream,
                       feat, rew, w_ih, b_ih, gi);
    hipLaunchKernelGGL(gru_scan, dim3(256), dim3(256), 0, stream,
                       gi, w_hh, b_hh, pairs, out);
}

// Round 8
// 29676.035 us; speedup vs baseline: 1.7156x; 1.7156x over previous
//
#include <hip/hip_runtime.h>
#include <stdint.h>

#define T_STEPS 8192
#define HID     1024
#define IN_F    2048
#define N3H     3072   // 3*HID
#define NREP    8      // exchange-buffer replicas (spread coherence-point lines)

// ---------------------------------------------------------------------------
// Exchange format: one u32 per h element; low 2 mantissa bits = step tag
// (step & 3). Double-buffered (buffer s&1 holds h of step s); stale content
// is from step s-2 (tag differs mod 4). Full-vector detection bounds wg skew
// below 2 steps, so neither past (s-4) nor future (s+4) mod-4 aliases can be
// observed. Producers store to every replica; wg g polls replica g&(NREP-1).
// h_0 = 0.0f with tag 0 == 0x0 -> zero-init.
//
// r8 poll: 2-deep pipelined probe ENTIRELY inside one asm block.
//  - alternating hard-clobbered quads v[60:63]/v[64:67]; s_waitcnt vmcnt(1)
//    between checks -> probe period = RTT/2 (vs serial RTT in r6);
//  - branching is SCALAR (v_cmp -> s_xor_b64 vcc,exec -> s_cbranch_scc0):
//    divergence impossible by construction; good words re-read are
//    monotone-safe;
//  - both exits drain vmcnt(0) BEFORE results move to output operands:
//    the compiler never observes an in-flight load (r2-r5 hazard class
//    structurally excluded). Topology unchanged from r6: wg-level probe
//    (256 threads x 16B = full 4KB vector), LDS share across the 4 waves
//    (r7's per-wave probing congested the coherence point 30x -> 3x slower).
// ---------------------------------------------------------------------------
__global__ void init_pairs(unsigned int* pairs) {
    int i = blockIdx.x * blockDim.x + threadIdx.x;
    if (i < 2 * NREP * HID) pairs[i] = 0u;
}

// fully self-contained 2-deep pipelined scoped poll (see header). Returns
// the 4 words of this thread's 16B slice, all tagged `want`.
__device__ __forceinline__ uint4 poll_pipelined(const unsigned int* p, unsigned int want) {
    unsigned int x, y, z, w;
    asm volatile(
        "global_load_dwordx4 v[60:63], %4, off sc0 sc1\n\t"
        "global_load_dwordx4 v[64:67], %4, off sc0 sc1\n"
        "Lpoll%=:\n\t"
        "s_waitcnt vmcnt(1)\n\t"
        "v_xor_b32 v68, %5, v60\n\t"
        "v_xor_b32 v69, %5, v61\n\t"
        "v_or_b32  v68, v68, v69\n\t"
        "v_xor_b32 v69, %5, v62\n\t"
        "v_or_b32  v68, v68, v69\n\t"
        "v_xor_b32 v69, %5, v63\n\t"
        "v_or_b32  v68, v68, v69\n\t"
        "v_and_b32 v68, 3, v68\n\t"
        "v_cmp_eq_u32 vcc, 0, v68\n\t"
        "s_xor_b64 s[20:21], vcc, exec\n\t"
        "s_cbranch_scc0 LdoneA%=\n\t"
        "global_load_dwordx4 v[60:63], %4, off sc0 sc1\n\t"
        "s_waitcnt vmcnt(1)\n\t"
        "v_xor_b32 v68, %5, v64\n\t"
        "v_xor_b32 v69, %5, v65\n\t"
        "v_or_b32  v68, v68, v69\n\t"
        "v_xor_b32 v69, %5, v66\n\t"
        "v_or_b32  v68, v68, v69\n\t"
        "v_xor_b32 v69, %5, v67\n\t"
        "v_or_b32  v68, v68, v69\n\t"
        "v_and_b32 v68, 3, v68\n\t"
        "v_cmp_eq_u32 vcc, 0, v68\n\t"
        "s_xor_b64 s[20:21], vcc, exec\n\t"
        "s_cbranch_scc0 LdoneB%=\n\t"
        "global_load_dwordx4 v[64:67], %4, off sc0 sc1\n\t"
        "s_branch Lpoll%=\n"
        "LdoneB%=:\n\t"
        "s_waitcnt vmcnt(0)\n\t"      // retire dangling A-load, THEN copy
        "v_mov_b32 v60, v64\n\t"
        "v_mov_b32 v61, v65\n\t"
        "v_mov_b32 v62, v66\n\t"
        "v_mov_b32 v63, v67\n"
        "LdoneA%=:\n\t"
        "s_waitcnt vmcnt(0)\n\t"      // retire dangling B-load (dest dead)
        "v_mov_b32 %0, v60\n\t"
        "v_mov_b32 %1, v61\n\t"
        "v_mov_b32 %2, v62\n\t"
        "v_mov_b32 %3, v63"
        : "=&v"(x), "=&v"(y), "=&v"(z), "=&v"(w)
        : "v"(p), "s"(want)
        : "memory", "vcc", "scc",
          "v60","v61","v62","v63","v64","v65","v66","v67","v68","v69",
          "s20","s21");
    uint4 r; r.x = x; r.y = y; r.z = z; r.w = w;
    return r;
}
__device__ __forceinline__ void store_scoped(unsigned int* p, unsigned int v) {
    asm volatile("global_store_dword %0, %1, off sc0 sc1"
                 :: "v"(p), "v"(v) : "memory");
}

// ---------------------------------------------------------------------------
// Phase 1: gi[t, j'] = x[t] . w_ih[j'] + b_ih[j']  (unchanged, ~1.4 ms)
// ---------------------------------------------------------------------------
#define GBM 64
#define GBN 64
#define GBK 32

__global__ __launch_bounds__(256) void gi_gemm(
    const float* __restrict__ feat,   // [8192][2048]
    const float* __restrict__ rew,    // [8192]
    const float* __restrict__ w_ih,   // [3072][2049]
    const float* __restrict__ b_ih,   // [3072]
    float* __restrict__ gi)           // [8192][3072]
{
    __shared__ float As[GBK][GBM + 4];
    __shared__ float Bs[GBK][GBN + 4];

    const int tid = threadIdx.x;
    const int n0 = blockIdx.x * GBN;
    const int t0 = blockIdx.y * GBM;
    const int tx = tid & 15, ty = tid >> 4;
    const int lr = tid >> 3;
    const int lc = (tid & 7) * 4;

    float acc[4][4] = {{0.f}};

    for (int k0 = 0; k0 < IN_F; k0 += GBK) {
#pragma unroll
        for (int hh = 0; hh < 2; hh++) {
            const int r = lr + 32 * hh;
            const float4 a = *(const float4*)(feat + (size_t)(t0 + r) * IN_F + k0 + lc);
            As[lc + 0][r] = a.x; As[lc + 1][r] = a.y;
            As[lc + 2][r] = a.z; As[lc + 3][r] = a.w;
            const float* brow = w_ih + (size_t)(n0 + r) * (IN_F + 1) + k0 + lc;
            Bs[lc + 0][r] = brow[0]; Bs[lc + 1][r] = brow[1];
            Bs[lc + 2][r] = brow[2]; Bs[lc + 3][r] = brow[3];
        }
        __syncthreads();
#pragma unroll
        for (int kk = 0; kk < GBK; kk++) {
            const float4 a = *(const float4*)&As[kk][ty * 4];
            const float4 b = *(const float4*)&Bs[kk][tx * 4];
            acc[0][0] += a.x * b.x; acc[0][1] += a.x * b.y; acc[0][2] += a.x * b.z; acc[0][3] += a.x * b.w;
            acc[1][0] += a.y * b.x; acc[1][1] += a.y * b.y; acc[1][2] += a.y * b.z; acc[1][3] += a.y * b.w;
            acc[2][0] += a.z * b.x; acc[2][1] += a.z * b.y; acc[2][2] += a.z * b.z; acc[2][3] += a.z * b.w;
            acc[3][0] += a.w * b.x; acc[3][1] += a.w * b.y; acc[3][2] += a.w * b.z; acc[3][3] += a.w * b.w;
        }
        __syncthreads();
    }

    const int m = t0 + ty * 4;
    const int n = n0 + tx * 4;
    float wlast[4], bi[4];
#pragma unroll
    for (int c = 0; c < 4; c++) {
        wlast[c] = w_ih[(size_t)(n + c) * (IN_F + 1) + IN_F];
        bi[c]    = b_ih[n + c];
    }
#pragma unroll
    for (int r = 0; r < 4; r++) {
        const float rwv = rew[m + r];
        float4 v;
        v.x = acc[r][0] + rwv * wlast[0] + bi[0];
        v.y = acc[r][1] + rwv * wlast[1] + bi[1];
        v.z = acc[r][2] + rwv * wlast[2] + bi[2];
        v.w = acc[r][3] + rwv * wlast[3] + bi[3];
        *(float4*)(gi + (size_t)(m + r) * N3H + n) = v;
    }
}

// ---------------------------------------------------------------------------
// Phase 2: persistent GRU scan (r6 topology). 256 wgs x 256 threads; wg g
// owns j in [4g,4g+4), one j per wave. Weights in static LDS (48 KB).
// h_lds double-buffered -> ONE __syncthreads per step (full compiler fence;
// its vmcnt drain is cheap: poll asm exits with vmcnt=0).
// r8 deltas: pipelined in-asm poll (RTT/2 detect); butterfly reduce so all
// lanes hold sums; all-lane redundant gates; 8 replica stores as ONE
// predicated issue by lanes 0..7 (stores honor exec -- masked issue safe).
// ---------------------------------------------------------------------------
__global__ __launch_bounds__(256, 2) void gru_scan(
    const float* __restrict__ gi,     // [8192][3072]
    const float* __restrict__ w_hh,   // [3072][1024]
    const float* __restrict__ b_hh,   // [3072]
    unsigned int* pairs,              // [2][NREP][1024] tagged fp32
    float* __restrict__ out)          // [1024]
{
    __shared__ float4 w_lds[3][4][HID / 4];  // 48 KB
    __shared__ float4 h_lds[2][HID / 4];     // 8 KB, double-buffered

    const int tid  = threadIdx.x;
    const int g    = blockIdx.x;      // 0..255
    const int j0   = g * 4;
    const int wave = tid >> 6;
    const int lane = tid & 63;
    const int myj  = j0 + wave;
    const int rep  = g & (NREP - 1);

#pragma unroll
    for (int r = 0; r < 12; r++) {
        const int gate = r >> 2, jl = r & 3;
        const float4* src = (const float4*)(w_hh + (size_t)(gate * HID + j0 + jl) * HID);
        w_lds[gate][jl][tid] = src[tid];
    }
    // uniform-address loads on all lanes: one broadcast fetch each
    const float b_r = b_hh[myj];
    const float b_z = b_hh[HID + myj];
    const float b_n = b_hh[2 * HID + myj];
    __syncthreads();

    for (int i = 0; i < T_STEPS; i++) {
        const int t = T_STEPS - 1 - i;
        const unsigned int want = (unsigned int)(i & 3);
        const unsigned int* rbuf =
            pairs + ((size_t)(i & 1) * NREP + rep) * HID + tid * 4;

        // gi prefetch: uniform-address (broadcast) loads on all lanes,
        // issued before the poll; drained under the poll's waits.
        const float* girow = gi + (size_t)t * N3H + myj;
        const float gi_r = girow[0];
        const float gi_z = girow[HID];
        const float gi_n = girow[2 * HID];

        // pipelined poll (RTT/2 detect), scalar-branch uniform, exits clean
        const uint4 v = poll_pipelined(rbuf, want);

        float4 hv;
        hv.x = __uint_as_float(v.x);
        hv.y = __uint_as_float(v.y);
        hv.z = __uint_as_float(v.z);
        hv.w = __uint_as_float(v.w);
        h_lds[i & 1][tid] = hv;
        __syncthreads();   // the ONE per-step barrier (full fence)

        // wave `wave` computes the 3 recurrent dots for j = myj
        float ar = 0.f, az = 0.f, an = 0.f;
        const float4* hb = h_lds[i & 1];
        const float4* wr = w_lds[0][wave];
        const float4* wz = w_lds[1][wave];
        const float4* wn = w_lds[2][wave];
#pragma unroll
        for (int m4 = 0; m4 < 4; m4++) {
            const int idx = lane + 64 * m4;
            const float4 h4 = hb[idx];
            const float4 r4 = wr[idx];
            const float4 z4 = wz[idx];
            const float4 n4 = wn[idx];
            ar += h4.x * r4.x + h4.y * r4.y + h4.z * r4.z + h4.w * r4.w;
            az += h4.x * z4.x + h4.y * z4.y + h4.z * z4.z + h4.w * z4.w;
            an += h4.x * n4.x + h4.y * n4.y + h4.z * n4.z + h4.w * n4.w;
        }
        // butterfly: full sums on ALL lanes
#pragma unroll
        for (int off = 32; off > 0; off >>= 1) {
            ar += __shfl_xor(ar, off);
            az += __shfl_xor(az, off);
            an += __shfl_xor(an, off);
        }

        // gates redundantly on all lanes; single predicated replica store
        const float hjold = ((const float*)h_lds[i & 1])[myj];  // broadcast
        const float r = 1.f / (1.f + __expf(-(gi_r + ar + b_r)));
        const float z = 1.f / (1.f + __expf(-(gi_z + az + b_z)));
        const float n = tanhf(gi_n + r * (an + b_n));
        const float hnew = (1.f - z) * n + z * hjold;

        if (i == T_STEPS - 1) {
            if (lane == 0) out[myj] = hnew;
        } else {
            const unsigned int pk =
                (__float_as_uint(hnew) & ~3u) | (unsigned int)((i + 1) & 3);
            unsigned int* sbase =
                pairs + (size_t)((i + 1) & 1) * NREP * HID + myj;
            if (lane < NREP) store_scoped(sbase + lane * HID, pk);
        }
        // no second barrier: next head touches h_lds[(i+1)&1] only, and the
        // global protocol blocks head i+2 (next write of h_lds[i&1]) until
        // every wg finished step i.
    }
}

// ---------------------------------------------------------------------------
extern "C" void kernel_launch(void* const* d_in, const int* in_sizes, int n_in,
                              void* d_out, int out_size, void* d_ws, size_t ws_size,
                              hipStream_t stream) {
    const float* feat = (const float*)d_in[0];  // [8192,2048]
    const float* rew  = (const float*)d_in[1];  // [8192]
    const float* w_ih = (const float*)d_in[2];  // [3072,2049]
    const float* w_hh = (const float*)d_in[3];  // [3072,1024]
    const float* b_ih = (const float*)d_in[4];  // [3072]
    const float* b_hh = (const float*)d_in[5];  // [3072]
    float* out = (float*)d_out;                 // [1024]

    float* gi = (float*)d_ws;                                   // 96 MB
    unsigned int* pairs =
        (unsigned int*)((char*)d_ws + (size_t)T_STEPS * N3H * sizeof(float));  // 64 KB

    hipLaunchKernelGGL(init_pairs, dim3((2 * NREP * HID + 255) / 256), dim3(256), 0, stream, pairs);
    hipLaunchKernelGGL(gi_gemm, dim3(N3H / GBN, T_STEPS / GBM), dim3(256), 0, stream,
                       feat, rew, w_ih, b_ih, gi);
    hipLaunchKernelGGL(gru_scan, dim3(256), dim3(256), 0, stream,
                       gi, w_hh, b_hh, pairs, out);
}